// Round 6
// baseline (145.993 us; speedup 1.0000x reference)
//
#include <hip/hip_runtime.h>
#include <cstdint>

#define BB 256
#define NN 128
#define DD 512
#define HH 512

typedef __attribute__((ext_vector_type(8))) short bf16x8;
typedef __attribute__((ext_vector_type(16))) float f32x16;
typedef unsigned short u16;

static __device__ __forceinline__ u16 f2bf(float f) {
    union { float f; uint32_t u; } v; v.f = f;
    uint32_t u = v.u;
    return (u16)((u + 0x7FFFu + ((u >> 16) & 1u)) >> 16);
}

// ---------------- W fp32 -> bf16 (once) ----------------
__global__ __launch_bounds__(256) void wconv_kernel(const float* __restrict__ W, u16* __restrict__ Wb) {
    int idx = (blockIdx.x * 256 + threadIdx.x) * 4;
    float4 v = *(const float4*)(W + idx);
    ushort4 o;
    o.x = f2bf(v.x); o.y = f2bf(v.y); o.z = f2bf(v.z); o.w = f2bf(v.w);
    *(ushort4*)(Wb + idx) = o;
}

// ---------------- Yt[b][h][m] = sum_d W[h][d] * X[b][m][d] ----------------
// grid 512 = (batch, m-half). 512 thr = 8 waves; wave w owns h in [64w, 64w+64).
// X-half in LDS (bf16, swizzled); W fragments read DIRECTLY from global (L2-resident).
// No barriers in the K-loop.
__global__ __launch_bounds__(512, 4) void yt_gemm_kernel(const float* __restrict__ X, const u16* __restrict__ Wb,
                                                         u16* __restrict__ Yt) {
    __shared__ __align__(16) u16 Xb[32768];   // [64 m][512 d] bf16, chunk-swizzled (64 KB)

    const int t = threadIdx.x;
    const int lane = t & 63;
    const int w = t >> 6;
    const int l31 = lane & 31, lh = lane >> 5;
    const int batch = blockIdx.x >> 1, mh = blockIdx.x & 1;

    // stage X half (64 rows x 512 d) fp32 -> bf16, chunk' = chunk ^ (row&7)
    const float* Xg = X + ((size_t)batch * NN + mh * 64) * DD;
    #pragma unroll
    for (int it = 0; it < 16; ++it) {
        int q = it * 512 + t;
        int r = q >> 7, c4 = q & 127;
        float4 v = *(const float4*)(Xg + (size_t)r * DD + c4 * 4);
        ushort4 o;
        o.x = f2bf(v.x); o.y = f2bf(v.y); o.z = f2bf(v.z); o.w = f2bf(v.w);
        *(ushort4*)((char*)Xb + r * 1024 + (((c4 >> 1) ^ (r & 7)) << 4) + ((c4 & 1) << 3)) = o;
    }
    __syncthreads();

    f32x16 acc[2][2];   // [hf][mi]; rows = h, cols = m
    #pragma unroll
    for (int hf = 0; hf < 2; ++hf)
        #pragma unroll
        for (int mi = 0; mi < 2; ++mi)
            #pragma unroll
            for (int r = 0; r < 16; ++r)
                acc[hf][mi][r] = 0.f;

    const u16* Wwave = Wb + (size_t)(w * 64) * DD;
    #pragma unroll 4
    for (int st = 0; st < 32; ++st) {
        const int c64 = st * 2 + lh;          // 16B chunk along d, 0..63
        bf16x8 af[2];
        #pragma unroll
        for (int hf = 0; hf < 2; ++hf)
            af[hf] = *(const bf16x8*)(Wwave + (size_t)(hf * 32 + l31) * DD + c64 * 8);
        bf16x8 bx[2];
        #pragma unroll
        for (int mi = 0; mi < 2; ++mi) {
            int m = mi * 32 + l31;
            bx[mi] = *(const bf16x8*)((const u16*)Xb + m * 512 + ((c64 ^ (m & 7)) * 8));
        }
        #pragma unroll
        for (int hf = 0; hf < 2; ++hf)
            #pragma unroll
            for (int mi = 0; mi < 2; ++mi)
                acc[hf][mi] = __builtin_amdgcn_mfma_f32_32x32x16_bf16(af[hf], bx[mi], acc[hf][mi], 0, 0, 0);
    }

    // store Yt[h][m]: lane holds col m = mi*32+l31; rows h via (r,lh)
    u16* Yg = Yt + (size_t)batch * (HH * NN) + mh * 64;
    #pragma unroll
    for (int hf = 0; hf < 2; ++hf)
        #pragma unroll
        for (int r = 0; r < 16; ++r) {
            int h = w * 64 + hf * 32 + (r & 3) + 8 * (r >> 2) + 4 * lh;
            #pragma unroll
            for (int mi = 0; mi < 2; ++mi)
                Yg[(size_t)h * NN + mi * 32 + l31] = f2bf(acc[hf][mi][r]);
        }
}

// ---------------- out = sigmoid(LN( (I + A_norm) @ Y + bias )) ----------------
// grid 512 = (batch, i-half); 512 thr; wave w owns h in [64w, 64w+64).
// M = A_norm + I in LDS; Yt fragments read DIRECTLY from global (L2-resident per batch).
__global__ __launch_bounds__(512, 4) void aggln_kernel(const float* __restrict__ A, const u16* __restrict__ Yt,
                                                       const float* __restrict__ bias, const float* __restrict__ lnw,
                                                       const float* __restrict__ lnb, float* __restrict__ out) {
    __shared__ __align__(16) u16 Ml[64 * 128];   // [64 i][128 m] bf16, chunk-swizzled (16 KB)
    __shared__ float Pss[512 * 2];               // [8 wavegroups][64 rows] (s, ss)
    __shared__ float musig[64 * 2];

    const int t = threadIdx.x;
    const int lane = t & 63, w = t >> 6, l31 = lane & 31, lh = lane >> 5;
    const int bid = ((int)blockIdx.x & 7) * 64 + ((int)blockIdx.x >> 3);   // XCD-chunked: batch pairs co-XCD
    const int batch = bid >> 1, ih = bid & 1;

    // A row loads (issue first)
    const int arow = t >> 3, seg = t & 7;
    const float* Ag = A + ((size_t)batch * NN + ih * 64 + arow) * NN + seg * 16;
    float4 av0 = *(const float4*)(Ag);
    float4 av1 = *(const float4*)(Ag + 4);
    float4 av2 = *(const float4*)(Ag + 8);
    float4 av3 = *(const float4*)(Ag + 12);

    float bias_v[2], lnw_v[2], lnb_v[2];
    #pragma unroll
    for (int fh = 0; fh < 2; ++fh) {
        int h = w * 64 + fh * 32 + l31;
        bias_v[fh] = bias[h];
        lnw_v[fh] = lnw[h];
        lnb_v[fh] = lnb[h];
    }

    // build M = A_norm + I (bf16, swizzled)
    {
        float s = av0.x + av0.y + av0.z + av0.w + av1.x + av1.y + av1.z + av1.w
                + av2.x + av2.y + av2.z + av2.w + av3.x + av3.y + av3.z + av3.w;
        s += __shfl_xor(s, 1);
        s += __shfl_xor(s, 2);
        s += __shfl_xor(s, 4);
        float inv = 1.0f / (s + 1e-6f);
        int ig = ih * 64 + arow;
        float fv[16] = {av0.x, av0.y, av0.z, av0.w, av1.x, av1.y, av1.z, av1.w,
                        av2.x, av2.y, av2.z, av2.w, av3.x, av3.y, av3.z, av3.w};
        ushort tmp[16];
        #pragma unroll
        for (int e = 0; e < 16; ++e) {
            int m = seg * 16 + e;
            float val = fv[e] * inv + (m == ig ? 1.0f : 0.0f);
            tmp[e] = f2bf(val);
        }
        *(uint4*)(Ml + arow * 128 + (((seg * 2) ^ (arow & 7)) * 8)) = *(const uint4*)&tmp[0];
        *(uint4*)(Ml + arow * 128 + (((seg * 2 + 1) ^ (arow & 7)) * 8)) = *(const uint4*)&tmp[8];
    }
    __syncthreads();

    // P[i][h] = sum_m M[i][m] * Yt[h][m]; B-frags direct from global
    const u16* Ytb = Yt + (size_t)batch * (HH * NN);
    f32x16 acc[2][2];
    #pragma unroll
    for (int fi = 0; fi < 2; ++fi)
        #pragma unroll
        for (int fh = 0; fh < 2; ++fh)
            #pragma unroll
            for (int r = 0; r < 16; ++r)
                acc[fi][fh][r] = 0.f;

    #pragma unroll
    for (int s8 = 0; s8 < 8; ++s8) {
        const int kc = s8 * 2 + lh;    // 16B m-chunk 0..15
        bf16x8 af[2], bw[2];
        #pragma unroll
        for (int fi = 0; fi < 2; ++fi) {
            int i = fi * 32 + l31;
            af[fi] = *(const bf16x8*)(Ml + i * 128 + ((kc ^ (i & 7)) * 8));
        }
        #pragma unroll
        for (int fh = 0; fh < 2; ++fh) {
            int h = w * 64 + fh * 32 + l31;
            bw[fh] = *(const bf16x8*)(Ytb + (size_t)h * NN + kc * 8);
        }
        #pragma unroll
        for (int fi = 0; fi < 2; ++fi)
            #pragma unroll
            for (int fh = 0; fh < 2; ++fh)
                acc[fi][fh] = __builtin_amdgcn_mfma_f32_32x32x16_bf16(af[fi], bw[fh], acc[fi][fh], 0, 0, 0);
    }

    // bias + per-row stats (row sums over this wave's 64 h)
    float rs[2][16], rss[2][16];
    #pragma unroll
    for (int fi = 0; fi < 2; ++fi)
        #pragma unroll
        for (int r = 0; r < 16; ++r) {
            float a0 = acc[fi][0][r] + bias_v[0];
            float a1 = acc[fi][1][r] + bias_v[1];
            acc[fi][0][r] = a0; acc[fi][1][r] = a1;
            rs[fi][r] = a0 + a1;
            rss[fi][r] = a0 * a0 + a1 * a1;
        }
    #pragma unroll
    for (int msk = 1; msk <= 16; msk <<= 1) {
        #pragma unroll
        for (int fi = 0; fi < 2; ++fi)
            #pragma unroll
            for (int r = 0; r < 16; ++r) {
                rs[fi][r] += __shfl_xor(rs[fi][r], msk);
                rss[fi][r] += __shfl_xor(rss[fi][r], msk);
            }
    }
    if (l31 == 0) {
        #pragma unroll
        for (int fi = 0; fi < 2; ++fi)
            #pragma unroll
            for (int r = 0; r < 16; ++r) {
                int row = fi * 32 + (r & 3) + 8 * (r >> 2) + 4 * lh;
                float2 v; v.x = rs[fi][r]; v.y = rss[fi][r];
                *(float2*)(Pss + (w * 64 + row) * 2) = v;
            }
    }
    __syncthreads();
    if (t < 64) {
        float s = 0.f, ss = 0.f;
        #pragma unroll
        for (int q = 0; q < 8; ++q) {
            float2 v = *(const float2*)(Pss + (q * 64 + t) * 2);
            s += v.x; ss += v.y;
        }
        float mean = s * (1.0f / 512.0f);
        float var = ss * (1.0f / 512.0f) - mean * mean;
        float2 mz; mz.x = mean; mz.y = rsqrtf(var + 1e-5f);
        *(float2*)(musig + t * 2) = mz;
    }
    __syncthreads();

    // LN + sigmoid + store
    #pragma unroll
    for (int fi = 0; fi < 2; ++fi)
        #pragma unroll
        for (int r = 0; r < 16; ++r) {
            int row = fi * 32 + (r & 3) + 8 * (r >> 2) + 4 * lh;
            float2 mz = *(const float2*)(musig + row * 2);
            #pragma unroll
            for (int fh = 0; fh < 2; ++fh) {
                float xn = (acc[fi][fh][r] - mz.x) * mz.y * lnw_v[fh] + lnb_v[fh];
                out[((size_t)batch * NN + ih * 64 + row) * HH + w * 64 + fh * 32 + l31] =
                    1.0f / (1.0f + __expf(-xn));
            }
        }
}

extern "C" void kernel_launch(void* const* d_in, const int* in_sizes, int n_in,
                              void* d_out, int out_size, void* d_ws, size_t ws_size,
                              hipStream_t stream) {
    const float* X = (const float*)d_in[0];
    const float* A = (const float*)d_in[1];
    const float* W = (const float*)d_in[2];
    const float* bias = (const float*)d_in[3];
    const float* lnw = (const float*)d_in[4];
    const float* lnb = (const float*)d_in[5];
    float* out = (float*)d_out;

    u16* Yt = (u16*)d_ws;                                  // B*H*N bf16 = 32 MB
    u16* Wb = (u16*)d_ws + (size_t)BB * HH * NN;           // H*D bf16 = 512 KB

    hipLaunchKernelGGL(wconv_kernel, dim3(256), dim3(256), 0, stream, W, Wb);
    hipLaunchKernelGGL(yt_gemm_kernel, dim3(512), dim3(512), 0, stream, X, Wb, Yt);
    hipLaunchKernelGGL(aggln_kernel, dim3(512), dim3(512), 0, stream, A, Yt, bias, lnw, lnb, out);
}

// Round 7
// 136.574 us; speedup vs baseline: 1.0690x; 1.0690x over previous
//
#include <hip/hip_runtime.h>
#include <cstdint>

#define BB 256
#define NN 128
#define DD 512
#define HH 512

typedef __attribute__((ext_vector_type(8))) short bf16x8;
typedef __attribute__((ext_vector_type(16))) float f32x16;
typedef unsigned short u16;

static __device__ __forceinline__ u16 f2bf(float f) {
    union { float f; uint32_t u; } v; v.f = f;
    uint32_t u = v.u;
    return (u16)((u + 0x7FFFu + ((u >> 16) & 1u)) >> 16);
}

static __device__ __forceinline__ void gload16(const u16* g, u16* l) {
    __builtin_amdgcn_global_load_lds((const __attribute__((address_space(1))) void*)g,
                                     (__attribute__((address_space(3))) void*)l, 16, 0, 0);
}

// ---------------- W fp32 -> bf16 (once) ----------------
__global__ __launch_bounds__(256) void wconv_kernel(const float* __restrict__ W, u16* __restrict__ Wb) {
    int idx = (blockIdx.x * 256 + threadIdx.x) * 4;
    float4 v = *(const float4*)(W + idx);
    ushort4 o;
    o.x = f2bf(v.x); o.y = f2bf(v.y); o.z = f2bf(v.z); o.w = f2bf(v.w);
    *(ushort4*)(Wb + idx) = o;
}

// ---------------- Xagg = (I + A_norm) @ X  (bf16 out) ----------------
// grid 256 (1/batch), 512 thr = 8 waves (2Mi x 4Nd), LDS: M 32K + Xt 128K = 160K
__global__ __launch_bounds__(512) void agg_kernel(const float* __restrict__ X, const float* __restrict__ A,
                                                  u16* __restrict__ Xagg) {
    __shared__ __align__(16) u16 Ms[128 * 128];   // [i][m], chunk c' = c ^ (i&15)
    __shared__ __align__(16) u16 Xt[512 * 128];   // [d][m], chunk c' = c ^ ((d>>2)&7)

    const int t = threadIdx.x;
    const int lane = t & 63, w = t >> 6, l31 = lane & 31, lh = lane >> 5;
    const int batch = blockIdx.x;

    // stage M = A_norm + I
    {
        const int row = t >> 2, seg = t & 3;
        const float* Ag = A + (size_t)batch * NN * NN + row * NN + seg * 32;
        float4 a[8];
        #pragma unroll
        for (int j = 0; j < 8; ++j) a[j] = *(const float4*)(Ag + j * 4);
        float s = 0.f;
        #pragma unroll
        for (int j = 0; j < 8; ++j) s += a[j].x + a[j].y + a[j].z + a[j].w;
        s += __shfl_xor(s, 1);
        s += __shfl_xor(s, 2);
        const float inv = 1.0f / (s + 1e-6f);
        #pragma unroll
        for (int c2 = 0; c2 < 4; ++c2) {
            u16 tmp[8];
            const float* pe = (const float*)&a[c2 * 2];
            #pragma unroll
            for (int e = 0; e < 8; ++e) {
                int m = seg * 32 + c2 * 8 + e;
                tmp[e] = f2bf(pe[e] * inv + (m == row ? 1.0f : 0.0f));
            }
            int c = seg * 4 + c2;
            *(uint4*)(Ms + row * 128 + ((c ^ (row & 15)) << 3)) = *(const uint4*)tmp;
        }
    }

    // stage Xt[d][m] = X[m][d] (bf16, swizzled scatter)
    const float* Xg = X + (size_t)batch * NN * DD;
    #pragma unroll
    for (int it = 0; it < 32; ++it) {
        int q = it * 512 + t;
        int m = q >> 7, c4 = q & 127;
        float4 v = *(const float4*)(Xg + (size_t)m * DD + c4 * 4);
        float fv[4] = {v.x, v.y, v.z, v.w};
        #pragma unroll
        for (int j = 0; j < 4; ++j) {
            int d = c4 * 4 + j;
            Xt[d * 128 + (((m >> 3) ^ ((d >> 2) & 7)) << 3) + (m & 7)] = f2bf(fv[j]);
        }
    }
    __syncthreads();

    const int wm = w >> 2, nd = w & 3;
    u16* Og = Xagg + (size_t)batch * NN * DD;
    #pragma unroll
    for (int dh = 0; dh < 2; ++dh) {
        f32x16 acc[2][2];
        #pragma unroll
        for (int fi = 0; fi < 2; ++fi)
            #pragma unroll
            for (int fd = 0; fd < 2; ++fd)
                #pragma unroll
                for (int r = 0; r < 16; ++r)
                    acc[fi][fd][r] = 0.f;

        #pragma unroll
        for (int ksl = 0; ksl < 8; ++ksl) {
            const int kc = ksl * 2 + lh;
            bf16x8 af[2], bx[2];
            #pragma unroll
            for (int fi = 0; fi < 2; ++fi) {
                int i = wm * 64 + fi * 32 + l31;
                af[fi] = *(const bf16x8*)(Ms + i * 128 + ((kc ^ (i & 15)) << 3));
            }
            #pragma unroll
            for (int fd = 0; fd < 2; ++fd) {
                int d = dh * 256 + nd * 64 + fd * 32 + l31;
                bx[fd] = *(const bf16x8*)(Xt + d * 128 + ((kc ^ ((d >> 2) & 7)) << 3));
            }
            #pragma unroll
            for (int fi = 0; fi < 2; ++fi)
                #pragma unroll
                for (int fd = 0; fd < 2; ++fd)
                    acc[fi][fd] = __builtin_amdgcn_mfma_f32_32x32x16_bf16(af[fi], bx[fd], acc[fi][fd], 0, 0, 0);
        }

        #pragma unroll
        for (int fi = 0; fi < 2; ++fi)
            #pragma unroll
            for (int r = 0; r < 16; ++r) {
                int i = wm * 64 + fi * 32 + (r & 3) + 8 * (r >> 2) + 4 * lh;
                #pragma unroll
                for (int fd = 0; fd < 2; ++fd) {
                    int d = dh * 256 + nd * 64 + fd * 32 + l31;
                    Og[(size_t)i * DD + d] = f2bf(acc[fi][fd][r]);
                }
            }
    }
}

// ---------------- out = sigmoid(LN( Xagg @ W^T + bias )) ----------------
// grid 512 = (batch, m-half); 512 thr = 8 waves; wave w -> h strip [64w, 64w+64)
// BK=32 double-buffered gload16 staging; LDS 72K -> 2 blocks/CU
__global__ __launch_bounds__(512, 4) void gemm_ln_kernel(const u16* __restrict__ Xagg, const u16* __restrict__ Wb,
                                                         const float* __restrict__ bias, const float* __restrict__ lnw,
                                                         const float* __restrict__ lnb, float* __restrict__ out) {
    __shared__ __align__(16) char smem[73728];   // W slabs 2x32K @0; Xa slabs 2x4K @65536
    float* Pss = (float*)smem;                   // overlay after K-loop: [8][64][2]
    float* musig = (float*)(smem + 4096);        // [64][2]

    const int t = threadIdx.x;
    const int lane = t & 63, w = t >> 6, l31 = lane & 31, lh = lane >> 5;
    const int batch = blockIdx.x >> 1, mh = blockIdx.x & 1;
    const u16* Xab = Xagg + ((size_t)batch * NN + mh * 64) * DD;

    float bias_v[2], lnw_v[2], lnb_v[2];
    #pragma unroll
    for (int fh = 0; fh < 2; ++fh) {
        int h = w * 64 + fh * 32 + l31;
        bias_v[fh] = bias[h];
        lnw_v[fh] = lnw[h];
        lnb_v[fh] = lnb[h];
    }

#define STAGE2(KS, BUF)                                                              \
    {                                                                                \
        const int k0_ = (KS) * 32;                                                   \
        u16* wl_ = (u16*)(smem + (BUF) * 32768);                                     \
        u16* xal_ = (u16*)(smem + 65536 + (BUF) * 4096);                             \
        _Pragma("unroll")                                                            \
        for (int i_ = 0; i_ < 4; ++i_) {                                             \
            int p_ = w * 256 + i_ * 64 + lane;                                       \
            int h_ = p_ >> 2;                                                        \
            int cc_ = (p_ & 3) ^ ((h_ >> 1) & 3);                                    \
            gload16(Wb + (size_t)h_ * DD + k0_ + cc_ * 8, wl_ + p_ * 8);             \
        }                                                                            \
        if (t < 256) {                                                               \
            int m_ = t >> 2;                                                         \
            int cc_ = (t & 3) ^ ((m_ >> 1) & 3);                                     \
            gload16(Xab + (size_t)m_ * DD + k0_ + cc_ * 8, xal_ + t * 8);            \
        }                                                                            \
    }

    f32x16 acc[2][2];
    #pragma unroll
    for (int fi = 0; fi < 2; ++fi)
        #pragma unroll
        for (int fh = 0; fh < 2; ++fh)
            #pragma unroll
            for (int r = 0; r < 16; ++r)
                acc[fi][fh][r] = 0.f;

    STAGE2(0, 0);
    for (int ks = 0; ks < 16; ++ks) {
        const int buf = ks & 1;
        if (ks < 15) {
            STAGE2(ks + 1, buf ^ 1);
            if (w < 4) asm volatile("s_waitcnt vmcnt(5)" ::: "memory");
            else       asm volatile("s_waitcnt vmcnt(4)" ::: "memory");
        } else {
            asm volatile("s_waitcnt vmcnt(0)" ::: "memory");
        }
        __builtin_amdgcn_s_barrier();
        asm volatile("" ::: "memory");

        const u16* wl = (const u16*)(smem + buf * 32768);
        const u16* xal = (const u16*)(smem + 65536 + buf * 4096);
        #pragma unroll
        for (int s2 = 0; s2 < 2; ++s2) {
            const int cc = s2 * 2 + lh;
            bf16x8 af[2], bw[2];
            #pragma unroll
            for (int fi = 0; fi < 2; ++fi) {
                int m = fi * 32 + l31;
                af[fi] = *(const bf16x8*)(xal + (m * 4 + (cc ^ ((m >> 1) & 3))) * 8);
            }
            #pragma unroll
            for (int fh = 0; fh < 2; ++fh) {
                int h = w * 64 + fh * 32 + l31;
                bw[fh] = *(const bf16x8*)(wl + (h * 4 + (cc ^ ((h >> 1) & 3))) * 8);
            }
            #pragma unroll
            for (int fi = 0; fi < 2; ++fi)
                #pragma unroll
                for (int fh = 0; fh < 2; ++fh)
                    acc[fi][fh] = __builtin_amdgcn_mfma_f32_32x32x16_bf16(af[fi], bw[fh], acc[fi][fh], 0, 0, 0);
        }
        asm volatile("" ::: "memory");
        __builtin_amdgcn_s_barrier();
    }
#undef STAGE2
    __syncthreads();   // slabs dead; overlay stats

    // bias + per-row partial stats over this wave's 64 h
    float rs[2][16], rss[2][16];
    #pragma unroll
    for (int fi = 0; fi < 2; ++fi)
        #pragma unroll
        for (int r = 0; r < 16; ++r) {
            float a0 = acc[fi][0][r] + bias_v[0];
            float a1 = acc[fi][1][r] + bias_v[1];
            acc[fi][0][r] = a0; acc[fi][1][r] = a1;
            rs[fi][r] = a0 + a1;
            rss[fi][r] = a0 * a0 + a1 * a1;
        }
    #pragma unroll
    for (int msk = 1; msk <= 16; msk <<= 1) {
        #pragma unroll
        for (int fi = 0; fi < 2; ++fi)
            #pragma unroll
            for (int r = 0; r < 16; ++r) {
                rs[fi][r] += __shfl_xor(rs[fi][r], msk);
                rss[fi][r] += __shfl_xor(rss[fi][r], msk);
            }
    }
    if (l31 == 0) {
        #pragma unroll
        for (int fi = 0; fi < 2; ++fi)
            #pragma unroll
            for (int r = 0; r < 16; ++r) {
                int row = fi * 32 + (r & 3) + 8 * (r >> 2) + 4 * lh;
                float2 v; v.x = rs[fi][r]; v.y = rss[fi][r];
                *(float2*)(Pss + (w * 64 + row) * 2) = v;
            }
    }
    __syncthreads();
    if (t < 64) {
        float s = 0.f, ss = 0.f;
        #pragma unroll
        for (int q = 0; q < 8; ++q) {
            float2 v = *(const float2*)(Pss + (q * 64 + t) * 2);
            s += v.x; ss += v.y;
        }
        float mean = s * (1.0f / 512.0f);
        float var = ss * (1.0f / 512.0f) - mean * mean;
        float2 mz; mz.x = mean; mz.y = rsqrtf(var + 1e-5f);
        *(float2*)(musig + t * 2) = mz;
    }
    __syncthreads();

    #pragma unroll
    for (int fi = 0; fi < 2; ++fi)
        #pragma unroll
        for (int r = 0; r < 16; ++r) {
            int row = fi * 32 + (r & 3) + 8 * (r >> 2) + 4 * lh;
            float2 mz = *(const float2*)(musig + row * 2);
            #pragma unroll
            for (int fh = 0; fh < 2; ++fh) {
                float xn = (acc[fi][fh][r] - mz.x) * mz.y * lnw_v[fh] + lnb_v[fh];
                out[((size_t)batch * NN + mh * 64 + row) * HH + w * 64 + fh * 32 + l31] =
                    1.0f / (1.0f + __expf(-xn));
            }
        }
}

extern "C" void kernel_launch(void* const* d_in, const int* in_sizes, int n_in,
                              void* d_out, int out_size, void* d_ws, size_t ws_size,
                              hipStream_t stream) {
    const float* X = (const float*)d_in[0];
    const float* A = (const float*)d_in[1];
    const float* W = (const float*)d_in[2];
    const float* bias = (const float*)d_in[3];
    const float* lnw = (const float*)d_in[4];
    const float* lnb = (const float*)d_in[5];
    float* out = (float*)d_out;

    u16* Xagg = (u16*)d_ws;                                  // B*N*D bf16 = 32 MB
    u16* Wb = (u16*)d_ws + (size_t)BB * NN * DD;             // H*D bf16 = 512 KB

    hipLaunchKernelGGL(wconv_kernel, dim3(256), dim3(256), 0, stream, W, Wb);
    hipLaunchKernelGGL(agg_kernel, dim3(256), dim3(512), 0, stream, X, A, Xagg);
    hipLaunchKernelGGL(gemm_ln_kernel, dim3(512), dim3(512), 0, stream, Xagg, Wb, bias, lnw, lnb, out);
}

// Round 9
// 87.621 us; speedup vs baseline: 1.6662x; 1.5587x over previous
//
#include <hip/hip_runtime.h>
#include <cstdint>

#define BB 256
#define NN 128
#define DD 512
#define HH 512

typedef __attribute__((ext_vector_type(8))) short bf16x8;
typedef __attribute__((ext_vector_type(16))) float f32x16;
typedef unsigned short u16;

static __device__ __forceinline__ u16 f2bf(float f) {
    union { float f; uint32_t u; } v; v.f = f;
    uint32_t u = v.u;
    return (u16)((u + 0x7FFFu + ((u >> 16) & 1u)) >> 16);
}

static __device__ __forceinline__ void gload16(const u16* g, u16* l) {
    __builtin_amdgcn_global_load_lds((const __attribute__((address_space(1))) void*)g,
                                     (__attribute__((address_space(3))) void*)l, 16, 0, 0);
}

// ---------------- W fp32 -> bf16 (once) ----------------
__global__ __launch_bounds__(256) void wconv_kernel(const float* __restrict__ W, u16* __restrict__ Wb) {
    int idx = (blockIdx.x * 256 + threadIdx.x) * 4;
    float4 v = *(const float4*)(W + idx);
    ushort4 o;
    o.x = f2bf(v.x); o.y = f2bf(v.y); o.z = f2bf(v.z); o.w = f2bf(v.w);
    *(ushort4*)(Wb + idx) = o;
}

// ================ FUSED: out = sigmoid(LN( ((I+A_norm)X) W^T + b )) ================
// 1 block per batch (256 blocks), 512 thr = 8 waves (wm = w>>2 in {0,1}, wn = w&3).
// LDS: [0,32K) Ms[128][128] -> W slabs 2x16K -> Pss/musig overlay
//      [32K,160K) Xt[512][128] -> Xagg halves [128][256] bf16 overlay
__global__ __launch_bounds__(512, 2) void fused_kernel(const float* __restrict__ X, const float* __restrict__ A,
                                                       const u16* __restrict__ Wb, const float* __restrict__ bias,
                                                       const float* __restrict__ lnw, const float* __restrict__ lnb,
                                                       float* __restrict__ out) {
    __shared__ __align__(16) char smem[163840];
    u16* Ms = (u16*)smem;                 // [128 i][128 m], chunk c' = c ^ (i&15)
    u16* Xt = (u16*)(smem + 32768);       // [512 d][128 m], chunk c' = c ^ ((d>>2)&7)
    float* Pss = (float*)smem;            // epilogue overlay: [4 wn][128 row][2]
    float* musig = (float*)(smem + 4096); // [128 row][2]

    const int t = threadIdx.x;
    const int lane = t & 63, w = t >> 6, l31 = lane & 31, lh = lane >> 5;
    const int batch = blockIdx.x;
    const int wm = w >> 2, wn = w & 3;

    // ---- Phase 1a: M = A_norm + I ----
    {
        const int row = t >> 2, seg = t & 3;
        const float* Ag = A + (size_t)batch * NN * NN + row * NN + seg * 32;
        float4 a[8];
        #pragma unroll
        for (int j = 0; j < 8; ++j) a[j] = *(const float4*)(Ag + j * 4);
        float s = 0.f;
        #pragma unroll
        for (int j = 0; j < 8; ++j) s += a[j].x + a[j].y + a[j].z + a[j].w;
        s += __shfl_xor(s, 1);
        s += __shfl_xor(s, 2);
        const float inv = 1.0f / (s + 1e-6f);
        #pragma unroll
        for (int c2 = 0; c2 < 4; ++c2) {
            u16 tmp[8];
            const float* pe = (const float*)&a[c2 * 2];
            #pragma unroll
            for (int e = 0; e < 8; ++e) {
                int m = seg * 32 + c2 * 8 + e;
                tmp[e] = f2bf(pe[e] * inv + (m == row ? 1.0f : 0.0f));
            }
            int c = seg * 4 + c2;
            *(uint4*)(Ms + row * 128 + ((c ^ (row & 15)) << 3)) = *(const uint4*)tmp;
        }
    }

    // ---- Phase 1b: Xt[d][m] = X[m][d] bf16 swizzled ----
    {
        const float* Xg = X + (size_t)batch * NN * DD;
        #pragma unroll
        for (int it = 0; it < 32; ++it) {
            int q = it * 512 + t;
            int m = q >> 7, c4 = q & 127;
            float4 v = *(const float4*)(Xg + (size_t)m * DD + c4 * 4);
            float fv[4] = {v.x, v.y, v.z, v.w};
            #pragma unroll
            for (int j = 0; j < 4; ++j) {
                int d = c4 * 4 + j;
                Xt[d * 128 + (((m >> 3) ^ ((d >> 2) & 7)) << 3) + (m & 7)] = f2bf(fv[j]);
            }
        }
    }
    __syncthreads();

    // ---- Phase 2: GEMM1 (M @ X) per d-half; overlay Xagg bf16 onto dead Xt half ----
    // Xagg half dh at byte 32768 + dh*65536: [128 i][256 dl], row stride 512B,
    // chunk cloc' = cloc ^ (i&7)
    #pragma unroll
    for (int dh = 0; dh < 2; ++dh) {
        f32x16 acc1[2][2];
        #pragma unroll
        for (int fi = 0; fi < 2; ++fi)
            #pragma unroll
            for (int fd = 0; fd < 2; ++fd)
                #pragma unroll
                for (int r = 0; r < 16; ++r)
                    acc1[fi][fd][r] = 0.f;

        #pragma unroll
        for (int ksl = 0; ksl < 8; ++ksl) {
            const int kc = ksl * 2 + lh;
            bf16x8 af[2], bx[2];
            #pragma unroll
            for (int fi = 0; fi < 2; ++fi) {
                int i = wm * 64 + fi * 32 + l31;
                af[fi] = *(const bf16x8*)(Ms + i * 128 + ((kc ^ (i & 15)) << 3));
            }
            #pragma unroll
            for (int fd = 0; fd < 2; ++fd) {
                int d = dh * 256 + wn * 64 + fd * 32 + l31;
                bx[fd] = *(const bf16x8*)(Xt + d * 128 + ((kc ^ ((d >> 2) & 7)) << 3));
            }
            #pragma unroll
            for (int fi = 0; fi < 2; ++fi)
                #pragma unroll
                for (int fd = 0; fd < 2; ++fd)
                    acc1[fi][fd] = __builtin_amdgcn_mfma_f32_32x32x16_bf16(af[fi], bx[fd], acc1[fi][fd], 0, 0, 0);
        }
        __syncthreads();   // all waves done reading Xt half dh

        char* Xa = smem + 32768 + dh * 65536;
        #pragma unroll
        for (int fi = 0; fi < 2; ++fi)
            #pragma unroll
            for (int r = 0; r < 16; ++r) {
                int i = wm * 64 + fi * 32 + (r & 3) + 8 * (r >> 2) + 4 * lh;
                #pragma unroll
                for (int fd = 0; fd < 2; ++fd) {
                    int dl = wn * 64 + fd * 32 + l31;
                    *(u16*)(Xa + i * 512 + (((dl >> 3) ^ (i & 7)) << 4) + (dl & 7) * 2) = f2bf(acc1[fi][fd][r]);
                }
            }
        __syncthreads();
    }

    // ---- Phase 3: GEMM2 (Xagg @ W^T), two static ch passes, syncthreads pipeline ----
    float bias_v[2][2], lnw_v[2][2], lnb_v[2][2];
    #pragma unroll
    for (int ch = 0; ch < 2; ++ch)
        #pragma unroll
        for (int fh = 0; fh < 2; ++fh) {
            int h = ch * 256 + wn * 64 + fh * 32 + l31;
            bias_v[ch][fh] = bias[h];
            lnw_v[ch][fh] = lnw[h];
            lnb_v[ch][fh] = lnb[h];
        }

    f32x16 acc[2][2][2];   // [ch][fi(m)][fh(h)] — all accesses static
    #pragma unroll
    for (int ch = 0; ch < 2; ++ch)
        #pragma unroll
        for (int fi = 0; fi < 2; ++fi)
            #pragma unroll
            for (int fh = 0; fh < 2; ++fh)
                #pragma unroll
                for (int r = 0; r < 16; ++r)
                    acc[ch][fi][fh][r] = 0.f;

#define STAGEW(CH, KS, BUF)                                                               \
    {                                                                                     \
        u16* dst_ = (u16*)(smem + (BUF) * 16384);                                         \
        _Pragma("unroll")                                                                 \
        for (int it_ = 0; it_ < 2; ++it_) {                                               \
            int q_ = it_ * 512 + t;                                                       \
            int h_ = q_ >> 2, cc_ = q_ & 3;                                               \
            gload16(Wb + (size_t)((CH) * 256 + h_) * DD + (KS) * 32 +                     \
                        ((cc_ ^ ((h_ >> 1) & 3)) * 8),                                    \
                    dst_ + q_ * 8);                                                       \
        }                                                                                 \
    }

#define GEMM2_PASS(CH)                                                                    \
    {                                                                                     \
        STAGEW(CH, 0, 0);                                                                 \
        __syncthreads();                                                                  \
        for (int ks = 0; ks < 16; ++ks) {                                                 \
            const int buf = ks & 1;                                                       \
            if (ks < 15) STAGEW(CH, ks + 1, buf ^ 1);                                     \
            const u16* wl = (const u16*)(smem + buf * 16384);                             \
            _Pragma("unroll")                                                             \
            for (int s2 = 0; s2 < 2; ++s2) {                                              \
                const int kc = s2 * 2 + lh;                                               \
                const int ccg = ks * 4 + kc;                                              \
                const int xdh = ccg >> 5, cloc = ccg & 31;                                \
                const char* Xa = smem + 32768 + xdh * 65536;                              \
                bf16x8 af[2], bw[2];                                                      \
                _Pragma("unroll")                                                         \
                for (int fi = 0; fi < 2; ++fi) {                                          \
                    int m = wm * 64 + fi * 32 + l31;                                      \
                    af[fi] = *(const bf16x8*)(Xa + m * 512 + ((cloc ^ (m & 7)) << 4));    \
                }                                                                         \
                _Pragma("unroll")                                                         \
                for (int fh = 0; fh < 2; ++fh) {                                          \
                    int hl = wn * 64 + fh * 32 + l31;                                     \
                    bw[fh] = *(const bf16x8*)(wl + hl * 32 + ((kc ^ ((hl >> 1) & 3)) * 8)); \
                }                                                                         \
                _Pragma("unroll")                                                         \
                for (int fi = 0; fi < 2; ++fi)                                            \
                    _Pragma("unroll")                                                     \
                    for (int fh = 0; fh < 2; ++fh)                                        \
                        acc[CH][fi][fh] = __builtin_amdgcn_mfma_f32_32x32x16_bf16(        \
                            af[fi], bw[fh], acc[CH][fi][fh], 0, 0, 0);                    \
            }                                                                             \
            __syncthreads();                                                              \
        }                                                                                 \
    }

    GEMM2_PASS(0);
    GEMM2_PASS(1);
#undef STAGEW
#undef GEMM2_PASS

    // ---- Phase 4: bias + LN stats + sigmoid + store ----
    float rs[2][16], rss[2][16];
    #pragma unroll
    for (int fi = 0; fi < 2; ++fi)
        #pragma unroll
        for (int r = 0; r < 16; ++r) {
            float s = 0.f, ss = 0.f;
            #pragma unroll
            for (int ch = 0; ch < 2; ++ch)
                #pragma unroll
                for (int fh = 0; fh < 2; ++fh) {
                    float a = acc[ch][fi][fh][r] + bias_v[ch][fh];
                    acc[ch][fi][fh][r] = a;
                    s += a; ss += a * a;
                }
            rs[fi][r] = s; rss[fi][r] = ss;
        }
    #pragma unroll
    for (int msk = 1; msk <= 16; msk <<= 1) {
        #pragma unroll
        for (int fi = 0; fi < 2; ++fi)
            #pragma unroll
            for (int r = 0; r < 16; ++r) {
                rs[fi][r] += __shfl_xor(rs[fi][r], msk);
                rss[fi][r] += __shfl_xor(rss[fi][r], msk);
            }
    }
    if (l31 == 0) {
        #pragma unroll
        for (int fi = 0; fi < 2; ++fi)
            #pragma unroll
            for (int r = 0; r < 16; ++r) {
                int row = wm * 64 + fi * 32 + (r & 3) + 8 * (r >> 2) + 4 * lh;
                float2 v; v.x = rs[fi][r]; v.y = rss[fi][r];
                *(float2*)(Pss + (wn * 128 + row) * 2) = v;
            }
    }
    __syncthreads();
    if (t < 128) {
        float s = 0.f, ss = 0.f;
        #pragma unroll
        for (int q = 0; q < 4; ++q) {
            float2 v = *(const float2*)(Pss + (q * 128 + t) * 2);
            s += v.x; ss += v.y;
        }
        float mean = s * (1.0f / 512.0f);
        float var = ss * (1.0f / 512.0f) - mean * mean;
        float2 mz; mz.x = mean; mz.y = rsqrtf(var + 1e-5f);
        *(float2*)(musig + t * 2) = mz;
    }
    __syncthreads();

    float* Og = out + (size_t)batch * NN * HH;
    #pragma unroll
    for (int fi = 0; fi < 2; ++fi)
        #pragma unroll
        for (int r = 0; r < 16; ++r) {
            int row = wm * 64 + fi * 32 + (r & 3) + 8 * (r >> 2) + 4 * lh;
            float2 mz = *(const float2*)(musig + row * 2);
            #pragma unroll
            for (int ch = 0; ch < 2; ++ch)
                #pragma unroll
                for (int fh = 0; fh < 2; ++fh) {
                    float xn = (acc[ch][fi][fh][r] - mz.x) * mz.y * lnw_v[ch][fh] + lnb_v[ch][fh];
                    Og[(size_t)row * HH + ch * 256 + wn * 64 + fh * 32 + l31] =
                        1.0f / (1.0f + __expf(-xn));
                }
        }
}

extern "C" void kernel_launch(void* const* d_in, const int* in_sizes, int n_in,
                              void* d_out, int out_size, void* d_ws, size_t ws_size,
                              hipStream_t stream) {
    const float* X = (const float*)d_in[0];
    const float* A = (const float*)d_in[1];
    const float* W = (const float*)d_in[2];
    const float* bias = (const float*)d_in[3];
    const float* lnw = (const float*)d_in[4];
    const float* lnb = (const float*)d_in[5];
    float* out = (float*)d_out;

    u16* Wb = (u16*)d_ws;   // H*D bf16 = 512 KB

    hipLaunchKernelGGL(wconv_kernel, dim3(256), dim3(256), 0, stream, W, Wb);
    hipLaunchKernelGGL(fused_kernel, dim3(256), dim3(512), 0, stream, X, A, Wb, bias, lnw, lnb, out);
}

// Round 10
// 87.595 us; speedup vs baseline: 1.6667x; 1.0003x over previous
//
#include <hip/hip_runtime.h>
#include <cstdint>

#define BB 256
#define NN 128
#define DD 512
#define HH 512

typedef __attribute__((ext_vector_type(8))) short bf16x8;
typedef __attribute__((ext_vector_type(16))) float f32x16;
typedef unsigned short u16;

static __device__ __forceinline__ u16 f2bf(float f) {
    union { float f; uint32_t u; } v; v.f = f;
    uint32_t u = v.u;
    return (u16)((u + 0x7FFFu + ((u >> 16) & 1u)) >> 16);
}

static __device__ __forceinline__ void gload16(const u16* g, u16* l) {
    __builtin_amdgcn_global_load_lds((const __attribute__((address_space(1))) void*)g,
                                     (__attribute__((address_space(3))) void*)l, 16, 0, 0);
}

// ---------------- W fp32 -> bf16 (once) ----------------
__global__ __launch_bounds__(256) void wconv_kernel(const float* __restrict__ W, u16* __restrict__ Wb) {
    int idx = (blockIdx.x * 256 + threadIdx.x) * 4;
    float4 v = *(const float4*)(W + idx);
    ushort4 o;
    o.x = f2bf(v.x); o.y = f2bf(v.y); o.z = f2bf(v.z); o.w = f2bf(v.w);
    *(ushort4*)(Wb + idx) = o;
}

// ================ FUSED: out = sigmoid(LN( ((I+A_norm)X) W^T + b )) ================
// 1 block per batch (256 blocks), 512 thr = 8 waves (wm = w>>2 in {0,1}, wn = w&3).
// LDS: [0,32K) Ms[128][128] -> W slabs 2x16K -> Pss/musig overlay
//      [32K,160K) Xt[512][128] -> Xagg halves [128][256] bf16 overlay
// launch_bounds min-waves arg MUST be 1: LDS caps at 1 block/CU; promising 2
// caps VGPR at 128 and spills the 128-reg accumulator (R9: +100 MB scratch).
__global__ __launch_bounds__(512, 1) void fused_kernel(const float* __restrict__ X, const float* __restrict__ A,
                                                       const u16* __restrict__ Wb, const float* __restrict__ bias,
                                                       const float* __restrict__ lnw, const float* __restrict__ lnb,
                                                       float* __restrict__ out) {
    __shared__ __align__(16) char smem[163840];
    u16* Ms = (u16*)smem;                 // [128 i][128 m], chunk c' = c ^ (i&15)
    u16* Xt = (u16*)(smem + 32768);       // [512 d][128 m], chunk c' = c ^ ((d>>2)&7)
    float* Pss = (float*)smem;            // epilogue overlay: [4 wn][128 row][2]
    float* musig = (float*)(smem + 4096); // [128 row][2]

    const int t = threadIdx.x;
    const int lane = t & 63, w = t >> 6, l31 = lane & 31, lh = lane >> 5;
    const int batch = blockIdx.x;
    const int wm = w >> 2, wn = w & 3;

    // ---- Phase 1a: M = A_norm + I ----
    {
        const int row = t >> 2, seg = t & 3;
        const float* Ag = A + (size_t)batch * NN * NN + row * NN + seg * 32;
        float4 a[8];
        #pragma unroll
        for (int j = 0; j < 8; ++j) a[j] = *(const float4*)(Ag + j * 4);
        float s = 0.f;
        #pragma unroll
        for (int j = 0; j < 8; ++j) s += a[j].x + a[j].y + a[j].z + a[j].w;
        s += __shfl_xor(s, 1);
        s += __shfl_xor(s, 2);
        const float inv = 1.0f / (s + 1e-6f);
        #pragma unroll
        for (int c2 = 0; c2 < 4; ++c2) {
            u16 tmp[8];
            const float* pe = (const float*)&a[c2 * 2];
            #pragma unroll
            for (int e = 0; e < 8; ++e) {
                int m = seg * 32 + c2 * 8 + e;
                tmp[e] = f2bf(pe[e] * inv + (m == row ? 1.0f : 0.0f));
            }
            int c = seg * 4 + c2;
            *(uint4*)(Ms + row * 128 + ((c ^ (row & 15)) << 3)) = *(const uint4*)tmp;
        }
    }

    // ---- Phase 1b: Xt[d][m] = X[m][d] bf16 swizzled ----
    {
        const float* Xg = X + (size_t)batch * NN * DD;
        #pragma unroll
        for (int it = 0; it < 32; ++it) {
            int q = it * 512 + t;
            int m = q >> 7, c4 = q & 127;
            float4 v = *(const float4*)(Xg + (size_t)m * DD + c4 * 4);
            float fv[4] = {v.x, v.y, v.z, v.w};
            #pragma unroll
            for (int j = 0; j < 4; ++j) {
                int d = c4 * 4 + j;
                Xt[d * 128 + (((m >> 3) ^ ((d >> 2) & 7)) << 3) + (m & 7)] = f2bf(fv[j]);
            }
        }
    }
    __syncthreads();

    // ---- Phase 2: GEMM1 (M @ X) per d-half; overlay Xagg bf16 onto dead Xt half ----
    // Xagg half dh at byte 32768 + dh*65536: [128 i][256 dl], row stride 512B,
    // chunk cloc' = cloc ^ (i&7)
    #pragma unroll
    for (int dh = 0; dh < 2; ++dh) {
        f32x16 acc1[2][2];
        #pragma unroll
        for (int fi = 0; fi < 2; ++fi)
            #pragma unroll
            for (int fd = 0; fd < 2; ++fd)
                #pragma unroll
                for (int r = 0; r < 16; ++r)
                    acc1[fi][fd][r] = 0.f;

        #pragma unroll
        for (int ksl = 0; ksl < 8; ++ksl) {
            const int kc = ksl * 2 + lh;
            bf16x8 af[2], bx[2];
            #pragma unroll
            for (int fi = 0; fi < 2; ++fi) {
                int i = wm * 64 + fi * 32 + l31;
                af[fi] = *(const bf16x8*)(Ms + i * 128 + ((kc ^ (i & 15)) << 3));
            }
            #pragma unroll
            for (int fd = 0; fd < 2; ++fd) {
                int d = dh * 256 + wn * 64 + fd * 32 + l31;
                bx[fd] = *(const bf16x8*)(Xt + d * 128 + ((kc ^ ((d >> 2) & 7)) << 3));
            }
            #pragma unroll
            for (int fi = 0; fi < 2; ++fi)
                #pragma unroll
                for (int fd = 0; fd < 2; ++fd)
                    acc1[fi][fd] = __builtin_amdgcn_mfma_f32_32x32x16_bf16(af[fi], bx[fd], acc1[fi][fd], 0, 0, 0);
        }
        __syncthreads();   // all waves done reading Xt half dh

        char* Xa = smem + 32768 + dh * 65536;
        #pragma unroll
        for (int fi = 0; fi < 2; ++fi)
            #pragma unroll
            for (int r = 0; r < 16; ++r) {
                int i = wm * 64 + fi * 32 + (r & 3) + 8 * (r >> 2) + 4 * lh;
                #pragma unroll
                for (int fd = 0; fd < 2; ++fd) {
                    int dl = wn * 64 + fd * 32 + l31;
                    *(u16*)(Xa + i * 512 + (((dl >> 3) ^ (i & 7)) << 4) + (dl & 7) * 2) = f2bf(acc1[fi][fd][r]);
                }
            }
        __syncthreads();
    }

    // ---- Phase 3: GEMM2 (Xagg @ W^T), two static ch passes, syncthreads pipeline ----
    float bias_v[2][2], lnw_v[2][2], lnb_v[2][2];
    #pragma unroll
    for (int ch = 0; ch < 2; ++ch)
        #pragma unroll
        for (int fh = 0; fh < 2; ++fh) {
            int h = ch * 256 + wn * 64 + fh * 32 + l31;
            bias_v[ch][fh] = bias[h];
            lnw_v[ch][fh] = lnw[h];
            lnb_v[ch][fh] = lnb[h];
        }

    f32x16 acc[2][2][2];   // [ch][fi(m)][fh(h)] — all accesses static
    #pragma unroll
    for (int ch = 0; ch < 2; ++ch)
        #pragma unroll
        for (int fi = 0; fi < 2; ++fi)
            #pragma unroll
            for (int fh = 0; fh < 2; ++fh)
                #pragma unroll
                for (int r = 0; r < 16; ++r)
                    acc[ch][fi][fh][r] = 0.f;

#define STAGEW(CH, KS, BUF)                                                               \
    {                                                                                     \
        u16* dst_ = (u16*)(smem + (BUF) * 16384);                                         \
        _Pragma("unroll")                                                                 \
        for (int it_ = 0; it_ < 2; ++it_) {                                               \
            int q_ = it_ * 512 + t;                                                       \
            int h_ = q_ >> 2, cc_ = q_ & 3;                                               \
            gload16(Wb + (size_t)((CH) * 256 + h_) * DD + (KS) * 32 +                     \
                        ((cc_ ^ ((h_ >> 1) & 3)) * 8),                                    \
                    dst_ + q_ * 8);                                                       \
        }                                                                                 \
    }

#define GEMM2_PASS(CH)                                                                    \
    {                                                                                     \
        STAGEW(CH, 0, 0);                                                                 \
        __syncthreads();                                                                  \
        for (int ks = 0; ks < 16; ++ks) {                                                 \
            const int buf = ks & 1;                                                       \
            if (ks < 15) STAGEW(CH, ks + 1, buf ^ 1);                                     \
            const u16* wl = (const u16*)(smem + buf * 16384);                             \
            _Pragma("unroll")                                                             \
            for (int s2 = 0; s2 < 2; ++s2) {                                              \
                const int kc = s2 * 2 + lh;                                               \
                const int ccg = ks * 4 + kc;                                              \
                const int xdh = ccg >> 5, cloc = ccg & 31;                                \
                const char* Xa = smem + 32768 + xdh * 65536;                              \
                bf16x8 af[2], bw[2];                                                      \
                _Pragma("unroll")                                                         \
                for (int fi = 0; fi < 2; ++fi) {                                          \
                    int m = wm * 64 + fi * 32 + l31;                                      \
                    af[fi] = *(const bf16x8*)(Xa + m * 512 + ((cloc ^ (m & 7)) << 4));    \
                }                                                                         \
                _Pragma("unroll")                                                         \
                for (int fh = 0; fh < 2; ++fh) {                                          \
                    int hl = wn * 64 + fh * 32 + l31;                                     \
                    bw[fh] = *(const bf16x8*)(wl + hl * 32 + ((kc ^ ((hl >> 1) & 3)) * 8)); \
                }                                                                         \
                _Pragma("unroll")                                                         \
                for (int fi = 0; fi < 2; ++fi)                                            \
                    _Pragma("unroll")                                                     \
                    for (int fh = 0; fh < 2; ++fh)                                        \
                        acc[CH][fi][fh] = __builtin_amdgcn_mfma_f32_32x32x16_bf16(        \
                            af[fi], bw[fh], acc[CH][fi][fh], 0, 0, 0);                    \
            }                                                                             \
            __syncthreads();                                                              \
        }                                                                                 \
    }

    GEMM2_PASS(0);
    GEMM2_PASS(1);
#undef STAGEW
#undef GEMM2_PASS

    // ---- Phase 4: bias + LN stats + sigmoid + store ----
    float rs[2][16], rss[2][16];
    #pragma unroll
    for (int fi = 0; fi < 2; ++fi)
        #pragma unroll
        for (int r = 0; r < 16; ++r) {
            float s = 0.f, ss = 0.f;
            #pragma unroll
            for (int ch = 0; ch < 2; ++ch)
                #pragma unroll
                for (int fh = 0; fh < 2; ++fh) {
                    float a = acc[ch][fi][fh][r] + bias_v[ch][fh];
                    acc[ch][fi][fh][r] = a;
                    s += a; ss += a * a;
                }
            rs[fi][r] = s; rss[fi][r] = ss;
        }
    #pragma unroll
    for (int msk = 1; msk <= 16; msk <<= 1) {
        #pragma unroll
        for (int fi = 0; fi < 2; ++fi)
            #pragma unroll
            for (int r = 0; r < 16; ++r) {
                rs[fi][r] += __shfl_xor(rs[fi][r], msk);
                rss[fi][r] += __shfl_xor(rss[fi][r], msk);
            }
    }
    if (l31 == 0) {
        #pragma unroll
        for (int fi = 0; fi < 2; ++fi)
            #pragma unroll
            for (int r = 0; r < 16; ++r) {
                int row = wm * 64 + fi * 32 + (r & 3) + 8 * (r >> 2) + 4 * lh;
                float2 v; v.x = rs[fi][r]; v.y = rss[fi][r];
                *(float2*)(Pss + (wn * 128 + row) * 2) = v;
            }
    }
    __syncthreads();
    if (t < 128) {
        float s = 0.f, ss = 0.f;
        #pragma unroll
        for (int q = 0; q < 4; ++q) {
            float2 v = *(const float2*)(Pss + (q * 128 + t) * 2);
            s += v.x; ss += v.y;
        }
        float mean = s * (1.0f / 512.0f);
        float var = ss * (1.0f / 512.0f) - mean * mean;
        float2 mz; mz.x = mean; mz.y = rsqrtf(var + 1e-5f);
        *(float2*)(musig + t * 2) = mz;
    }
    __syncthreads();

    float* Og = out + (size_t)batch * NN * HH;
    #pragma unroll
    for (int fi = 0; fi < 2; ++fi)
        #pragma unroll
        for (int r = 0; r < 16; ++r) {
            int row = wm * 64 + fi * 32 + (r & 3) + 8 * (r >> 2) + 4 * lh;
            float2 mz = *(const float2*)(musig + row * 2);
            #pragma unroll
            for (int ch = 0; ch < 2; ++ch)
                #pragma unroll
                for (int fh = 0; fh < 2; ++fh) {
                    float xn = (acc[ch][fi][fh][r] - mz.x) * mz.y * lnw_v[ch][fh] + lnb_v[ch][fh];
                    Og[(size_t)row * HH + ch * 256 + wn * 64 + fh * 32 + l31] =
                        1.0f / (1.0f + __expf(-xn));
                }
        }
}

extern "C" void kernel_launch(void* const* d_in, const int* in_sizes, int n_in,
                              void* d_out, int out_size, void* d_ws, size_t ws_size,
                              hipStream_t stream) {
    const float* X = (const float*)d_in[0];
    const float* A = (const float*)d_in[1];
    const float* W = (const float*)d_in[2];
    const float* bias = (const float*)d_in[3];
    const float* lnw = (const float*)d_in[4];
    const float* lnb = (const float*)d_in[5];
    float* out = (float*)d_out;

    u16* Wb = (u16*)d_ws;   // H*D bf16 = 512 KB

    hipLaunchKernelGGL(wconv_kernel, dim3(256), dim3(256), 0, stream, W, Wb);
    hipLaunchKernelGGL(fused_kernel, dim3(256), dim3(512), 0, stream, X, A, Wb, bias, lnw, lnb, out);
}